// Round 8
// baseline (1063.591 us; speedup 1.0000x reference)
//
#include <hip/hip_runtime.h>
#include <stdint.h>

#define NT 512
#define K1 -1.44269504f
#define K2 -2.88539008f

typedef __attribute__((ext_vector_type(8))) __bf16 bf16x8;
typedef __attribute__((ext_vector_type(8))) unsigned short ushort8;
typedef __attribute__((ext_vector_type(4))) float f32x4;

static __device__ __forceinline__ unsigned short f2bf(float f) {
    union { float f; uint32_t u; } v; v.f = f;
    uint32_t r = v.u + 0x7fffu + ((v.u >> 16) & 1u);   // RNE
    return (unsigned short)(r >> 16);
}

#if __has_builtin(__builtin_amdgcn_exp2f)
#define EXP2F(x) __builtin_amdgcn_exp2f(x)
#else
#define EXP2F(x) __expf((x) * 0.69314718f)
#endif

static __device__ __forceinline__ uint32_t pk_bf16(float lo, float hi) {
#if __has_builtin(__builtin_amdgcn_cvt_pk_bf16_f32)
    return __builtin_bit_cast(uint32_t, __builtin_amdgcn_cvt_pk_bf16_f32(lo, hi));
#else
    return ((uint32_t)f2bf(hi) << 16) | (uint32_t)f2bf(lo);
#endif
}

static __device__ __forceinline__ float exp2c(float t) {
    return EXP2F(fminf(t, 20.0f));
}
// 4 reciprocals for the price of 1: o[i] = 1/d[i]
static __device__ __forceinline__ void rcp4v(const float* d, float* o) {
    float ab = d[0] * d[1], cd = d[2] * d[3];
    float r = __builtin_amdgcn_rcpf(ab * cd);
    float rcd = cd * r, rab = ab * r;
    o[0] = d[1] * rcd; o[1] = d[0] * rcd;
    o[2] = d[3] * rab; o[3] = d[2] * rab;
}
// LSTM cell for 4 rows. z[g][i] pre-bias gate values; cs[g] = bias*k folded consts.
static __device__ __forceinline__ void cell4(const f32x4* z, const float* cs,
                                             float* c, float* h) {
    float den[4], si[4], sf[4], tg[4], so[4], inv[4];
#pragma unroll
    for (int i = 0; i < 4; ++i) den[i] = 1.0f + exp2c(fmaf(z[0][i], K1, cs[0]));
    rcp4v(den, si);
#pragma unroll
    for (int i = 0; i < 4; ++i) den[i] = 1.0f + exp2c(fmaf(z[1][i], K1, cs[1]));
    rcp4v(den, sf);
#pragma unroll
    for (int i = 0; i < 4; ++i) den[i] = 1.0f + exp2c(fmaf(z[2][i], K2, cs[2]));
    rcp4v(den, inv);
#pragma unroll
    for (int i = 0; i < 4; ++i) tg[i] = fmaf(2.0f, inv[i], -1.0f);
#pragma unroll
    for (int i = 0; i < 4; ++i) den[i] = 1.0f + exp2c(fmaf(z[3][i], K1, cs[3]));
    rcp4v(den, so);
#pragma unroll
    for (int i = 0; i < 4; ++i) c[i] = fmaf(sf[i], c[i], si[i] * tg[i]);
#pragma unroll
    for (int i = 0; i < 4; ++i) den[i] = 1.0f + exp2c(c[i] * K2);
    rcp4v(den, inv);
#pragma unroll
    for (int i = 0; i < 4; ++i) h[i] = so[i] * fmaf(2.0f, inv[i], -1.0f);
}
static __device__ __forceinline__ bf16x8 ld8(const unsigned short* p) {
    return __builtin_bit_cast(bf16x8, *(const ushort8*)p);
}
static __device__ __forceinline__ float swz(float v, int imm) {
    int r;
    if (imm == 0x0010) r = __builtin_amdgcn_ds_swizzle(__builtin_bit_cast(int, v), 0x0010);
    else               r = __builtin_amdgcn_ds_swizzle(__builtin_bit_cast(int, v), 0x0410);
    return __builtin_bit_cast(float, r);
}

// ---- prep: identical packing to round 7 ----
__global__ void prep_kernel(
    const float* __restrict__ emb_W, const float* __restrict__ emb_b,
    const float* __restrict__ enc_Wih, const float* __restrict__ enc_Whh,
    const float* __restrict__ dec_Wih, const float* __restrict__ dec_Whh,
    const float* __restrict__ enc_bih, const float* __restrict__ enc_bhh,
    const float* __restrict__ dec_bih, const float* __restrict__ dec_bhh,
    unsigned short* __restrict__ W0p, unsigned short* __restrict__ W1p,
    float* __restrict__ benc, float* __restrict__ bdec,
    float* __restrict__ Me, float* __restrict__ Md,
    float* __restrict__ ve, float* __restrict__ vd)
{
    int idx = blockIdx.x * blockDim.x + threadIdx.x;
    if (idx < 2 * 512 * 256) {
        int net = idx >> 17;
        int rem = idx & 131071;
        int n = rem >> 8, k = rem & 255;
        const float* Wih = net ? dec_Wih : enc_Wih;
        const float* Whh = net ? dec_Whh : enc_Whh;
        float v = (k < 128) ? Wih[(size_t)(512 + n) * 128 + k]
                            : Whh[(size_t)(512 + n) * 128 + k - 128];
        W1p[(size_t)net * 131072 + rem] = f2bf(v);
    }
    if (idx < 2 * 512 * 128) {
        int net = idx >> 16;
        int rem = idx & 65535;
        int j = rem & 7, quad = (rem >> 3) & 3, ln = (rem >> 5) & 15;
        int w = (rem >> 9) & 7, g = (rem >> 12) & 3, c = (rem >> 14) & 3;
        int n = g * 128 + w * 16 + ln;
        int k = c * 32 + quad * 8 + j;
        const float* Whh = net ? dec_Whh : enc_Whh;
        W0p[(size_t)net * 65536 + rem] = f2bf(Whh[(size_t)n * 128 + k]);
    }
    if (idx < 2048) {
        int net = idx >> 10;
        int rem = idx & 1023;
        float v = net ? (dec_bih[rem] + dec_bhh[rem]) : (enc_bih[rem] + enc_bhh[rem]);
        (net ? bdec : benc)[rem] = v;
    }
    if (idx < 1024) {
        int net = idx >> 9, n = idx & 511;
        const float* Wih = net ? dec_Wih : enc_Wih;
        float m0 = 0.f, m1 = 0.f, vv = 0.f;
        for (int k = 0; k < 128; ++k) {
            float wv = Wih[(size_t)n * 128 + k];
            m0 += wv * emb_W[k * 2 + 0];
            m1 += wv * emb_W[k * 2 + 1];
            vv += wv * emb_b[k];
        }
        float* M = net ? Md : Me;
        float* V = net ? vd : ve;
        M[n * 2 + 0] = m0; M[n * 2 + 1] = m1; V[n] = vv;
    }
}

__global__ __launch_bounds__(NT, 2) void lstm_kernel(
    const float* __restrict__ hist,
    const unsigned short* __restrict__ W0p, const unsigned short* __restrict__ W1p,
    const float* __restrict__ benc, const float* __restrict__ bdec,
    const float* __restrict__ Me, const float* __restrict__ Md,
    const float* __restrict__ ve, const float* __restrict__ vd,
    const float* __restrict__ out_W, const float* __restrict__ out_b,
    float* __restrict__ out)
{
    __shared__ __align__(16) unsigned short A1s[2 * 4096];
    __shared__ __align__(16) unsigned short W0Ls[65536];
    __shared__ __align__(16) float histL[16 * 120];

    const int tid = threadIdx.x;
    const int lane = tid & 63;
    const int w = tid >> 6;
    const int ln = lane & 15;
    const int quad = lane >> 4;
    const int row0 = blockIdx.x * 16;
    const int cc0 = w * 16 + ln;
    const int cg = (cc0 >> 3) & 3;

    const unsigned short* a1r = A1s + ln * 32 + ((quad ^ ((ln >> 2) & 3)) * 8);
    unsigned short* a1w = A1s + (cc0 >> 5) * 512 + quad * 128 + ((cg ^ quad) * 8) + (ln & 7);
    // two W0 bases so every read uses a 16-bit immediate offset
    const unsigned short* w0bA = W0Ls + w * 512 + ln * 32 + ((quad ^ ((ln >> 1) & 3)) * 8);
    const unsigned short* w0bB = w0bA + 32768;

    for (int e = tid; e < 256; e += NT) ((uint4*)A1s)[256 + e] = make_uint4(0u, 0u, 0u, 0u);
    for (int e = tid; e < 480; e += NT)
        ((float4*)histL)[e] = ((const float4*)(hist + (size_t)row0 * 120))[e];

    const int nidx = (ln < 2) ? ln : 0;
    const float outbL = out_b[nidx];
    bf16x8 ow[4];
#pragma unroll
    for (int c = 0; c < 4; ++c) {
        unsigned short tmp[8];
#pragma unroll
        for (int j = 0; j < 8; ++j)
            tmp[j] = f2bf(out_W[nidx * 128 + c * 32 + quad * 8 + j]);
        ow[c] = __builtin_bit_cast(bf16x8, *(ushort8*)tmp);
    }

    bf16x8 wl[4][8];                      // persistent layer1 weights
    float M0c[4], M1c[4];
    float cb0v[4], cb0_[4], cb1[4];       // folded bias*k constants
    float c0r[4] = {0.f, 0.f, 0.f, 0.f};
    float c1r[4] = {0.f, 0.f, 0.f, 0.f};
    const f32x4 fz = {0.f, 0.f, 0.f, 0.f};

    auto load_consts = [&](const float* bb, const float* M, const float* V,
                           const unsigned short* W1) {
#pragma unroll
        for (int g = 0; g < 4; ++g) {
            const int n = g * 128 + cc0;
#pragma unroll
            for (int q = 0; q < 8; ++q)
                wl[g][q] = ld8(W1 + (size_t)n * 256 + quad * 8 + q * 32);
            const float kk = (g == 2) ? K2 : K1;
            M0c[g] = M[n * 2 + 0];
            M1c[g] = M[n * 2 + 1];
            cb0v[g] = (bb[n] + V[n]) * kk;
            cb0_[g] = bb[n] * kk;
            cb1[g]  = bb[512 + n] * kk;
        }
    };
    auto copy_w0 = [&](const unsigned short* src) {
        for (int e = tid; e < 8192; e += NT) {
            int d = (e & ~3) | ((e & 3) ^ ((e >> 3) & 3));
            ((uint4*)W0Ls)[d] = ((const uint4*)src)[e];
        }
    };
    auto w0frag = [&](int c, int g) {   // c,g compile-time under unroll
        return ld8(((c < 2) ? w0bA : w0bB) + (c & 1) * 16384 + g * 4096);
    };
    auto store_h = [&](unsigned short* base, const float* h) {
        uint32_t p01 = pk_bf16(h[0], h[1]);
        uint32_t p23 = pk_bf16(h[2], h[3]);
        base[0]  = (unsigned short)p01;
        base[32] = (unsigned short)(p01 >> 16);
        base[64] = (unsigned short)p23;
        base[96] = (unsigned short)(p23 >> 16);
    };

    copy_w0(W0p);
    load_consts(benc, Me, ve, W1p);
    __syncthreads();

    // prologue: h0(0) = f(x(0), h=0, c=0) -> buf0 chunks 0..3
    {
        f32x4 z[4];
#pragma unroll
        for (int i = 0; i < 4; ++i) {
            float x0 = hist[(size_t)(row0 + quad * 4 + i) * 120 + 0];
            float x1 = hist[(size_t)(row0 + quad * 4 + i) * 120 + 1];
#pragma unroll
            for (int g = 0; g < 4; ++g) z[g][i] = fmaf(M0c[g], x0, M1c[g] * x1);
        }
        float hv[4];
        cell4(z, cb0v, c0r, hv);
        store_h(a1w, hv);
    }
    __syncthreads();

    // ======= encoder superphase S_t: layer1(t) + layer0(t+1), 1 barrier =======
    auto enc_step = [&](int t, int buf) {
        bf16x8 af[8];
#pragma unroll
        for (int q = 0; q < 8; ++q)
            af[q] = ld8(a1r + buf * 4096 + q * 512);
        f32x4 acc1[4];
#pragma unroll
        for (int g = 0; g < 4; ++g)
            acc1[g] = __builtin_amdgcn_mfma_f32_16x16x32_bf16(af[0], wl[g][0], fz, 0, 0, 0);
#pragma unroll
        for (int q = 1; q < 8; ++q)
#pragma unroll
            for (int g = 0; g < 4; ++g)
                acc1[g] = __builtin_amdgcn_mfma_f32_16x16x32_bf16(af[q], wl[g][q], acc1[g], 0, 0, 0);
        f32x4 acc0[4];
#pragma unroll
        for (int g = 0; g < 4; ++g)
            acc0[g] = __builtin_amdgcn_mfma_f32_16x16x32_bf16(af[0], w0frag(0, g), fz, 0, 0, 0);
#pragma unroll
        for (int c = 1; c < 4; ++c)
#pragma unroll
            for (int g = 0; g < 4; ++g)
                acc0[g] = __builtin_amdgcn_mfma_f32_16x16x32_bf16(af[c], w0frag(c, g), acc0[g], 0, 0, 0);
        float hv[4];
        cell4(acc1, cb1, c1r, hv);                       // layer1(t)
        store_h(a1w + (buf ^ 1) * 4096 + 2048, hv);
        f32x4 z0[4];
#pragma unroll
        for (int i = 0; i < 4; ++i) {
            float2 pv = *(const float2*)&histL[(quad * 4 + i) * 120 + 2 * (t + 1)];
#pragma unroll
            for (int g = 0; g < 4; ++g)
                z0[g][i] = fmaf(M0c[g], pv.x, fmaf(M1c[g], pv.y, acc0[g][i]));
        }
        cell4(z0, cb0v, c0r, hv);                        // layer0(t+1)
        store_h(a1w + (buf ^ 1) * 4096, hv);
        __syncthreads();
    };

    for (int t = 0; t < 58; t += 2) { enc_step(t, 0); enc_step(t + 1, 1); }
    enc_step(58, 0);

    // ======= S_59: layer1_enc(59); swap to decoder; layer0_dec(0) =======
    {
        bf16x8 af[8];
#pragma unroll
        for (int q = 0; q < 8; ++q)
            af[q] = ld8(a1r + 4096 + q * 512);
        f32x4 acc1[4];
#pragma unroll
        for (int g = 0; g < 4; ++g)
            acc1[g] = __builtin_amdgcn_mfma_f32_16x16x32_bf16(af[0], wl[g][0], fz, 0, 0, 0);
#pragma unroll
        for (int q = 1; q < 8; ++q)
#pragma unroll
            for (int g = 0; g < 4; ++g)
                acc1[g] = __builtin_amdgcn_mfma_f32_16x16x32_bf16(af[q], wl[g][q], acc1[g], 0, 0, 0);
        float hv[4];
        cell4(acc1, cb1, c1r, hv);
        store_h(a1w + 2048, hv);                         // h1(59) -> buf0[4..7]
        copy_w0(W0p + 65536);
        load_consts(bdec, Md, vd, W1p + 131072);
        __syncthreads();
        f32x4 acc0[4];
#pragma unroll
        for (int g = 0; g < 4; ++g)
            acc0[g] = __builtin_amdgcn_mfma_f32_16x16x32_bf16(af[0], w0frag(0, g), fz, 0, 0, 0);
#pragma unroll
        for (int c = 1; c < 4; ++c)
#pragma unroll
            for (int g = 0; g < 4; ++g)
                acc0[g] = __builtin_amdgcn_mfma_f32_16x16x32_bf16(af[c], w0frag(c, g), acc0[g], 0, 0, 0);
        cell4(acc0, cb0_, c0r, hv);                      // x = 0 at d=0
        store_h(a1w, hv);                                // h0_d(0) -> buf0[0..3]
        __syncthreads();
    }

    // ======= decoder D_d: ph1 layer1(d)+W0·h0(d); ph2 proj(d)+layer0(d+1) =======
    auto dec_step = [&](int d, int buf) {
        bf16x8 af[8];
#pragma unroll
        for (int q = 0; q < 8; ++q)
            af[q] = ld8(a1r + buf * 4096 + q * 512);
        f32x4 acc1[4];
#pragma unroll
        for (int g = 0; g < 4; ++g)
            acc1[g] = __builtin_amdgcn_mfma_f32_16x16x32_bf16(af[0], wl[g][0], fz, 0, 0, 0);
#pragma unroll
        for (int q = 1; q < 8; ++q)
#pragma unroll
            for (int g = 0; g < 4; ++g)
                acc1[g] = __builtin_amdgcn_mfma_f32_16x16x32_bf16(af[q], wl[g][q], acc1[g], 0, 0, 0);
        f32x4 acc0[4];
#pragma unroll
        for (int g = 0; g < 4; ++g)
            acc0[g] = __builtin_amdgcn_mfma_f32_16x16x32_bf16(af[0], w0frag(0, g), fz, 0, 0, 0);
#pragma unroll
        for (int c = 1; c < 4; ++c)
#pragma unroll
            for (int g = 0; g < 4; ++g)
                acc0[g] = __builtin_amdgcn_mfma_f32_16x16x32_bf16(af[c], w0frag(c, g), acc0[g], 0, 0, 0);
        float hv[4];
        cell4(acc1, cb1, c1r, hv);                       // layer1(d)
        store_h(a1w + (buf ^ 1) * 4096 + 2048, hv);
        __syncthreads();
        // phase 2: projection of h1(d)
        f32x4 pa = fz, pb = fz;
        pa = __builtin_amdgcn_mfma_f32_16x16x32_bf16(ld8(a1r + (buf ^ 1) * 4096 + 4 * 512), ow[0], pa, 0, 0, 0);
        pb = __builtin_amdgcn_mfma_f32_16x16x32_bf16(ld8(a1r + (buf ^ 1) * 4096 + 5 * 512), ow[1], pb, 0, 0, 0);
        pa = __builtin_amdgcn_mfma_f32_16x16x32_bf16(ld8(a1r + (buf ^ 1) * 4096 + 6 * 512), ow[2], pa, 0, 0, 0);
        pb = __builtin_amdgcn_mfma_f32_16x16x32_bf16(ld8(a1r + (buf ^ 1) * 4096 + 7 * 512), ow[3], pb, 0, 0, 0);
        float pd[4];
#pragma unroll
        for (int i = 0; i < 4; ++i) pd[i] = pa[i] + pb[i] + outbL;
        if (w == 0 && ln < 2) {
#pragma unroll
            for (int i = 0; i < 4; ++i)
                out[(size_t)(row0 + quad * 4 + i) * 720 + (size_t)d * 2 + ln] = pd[i];
        }
        f32x4 z0[4];
#pragma unroll
        for (int i = 0; i < 4; ++i) {
            float p0 = swz(pd[i], 0x0010);
            float p1 = swz(pd[i], 0x0410);
#pragma unroll
            for (int g = 0; g < 4; ++g)
                z0[g][i] = fmaf(M0c[g], p0, fmaf(M1c[g], p1, acc0[g][i]));
        }
        cell4(z0, cb0v, c0r, hv);                        // layer0(d+1)
        store_h(a1w + (buf ^ 1) * 4096, hv);
        __syncthreads();
    };

    for (int d = 0; d < 360; d += 2) { dec_step(d, 0); dec_step(d + 1, 1); }

    // final projection (h1(359) lives in buffer 0)
    {
        f32x4 pacc = fz;
#pragma unroll
        for (int c = 0; c < 4; ++c) {
            bf16x8 ah = ld8(a1r + 0 * 4096 + (4 + c) * 512);
            pacc = __builtin_amdgcn_mfma_f32_16x16x32_bf16(ah, ow[c], pacc, 0, 0, 0);
        }
        if (w == 0 && ln < 2) {
#pragma unroll
            for (int i = 0; i < 4; ++i)
                out[(size_t)(row0 + quad * 4 + i) * 720 + 359 * 2 + ln] = pacc[i] + outbL;
        }
    }
}

extern "C" void kernel_launch(void* const* d_in, const int* in_sizes, int n_in,
                              void* d_out, int out_size, void* d_ws, size_t ws_size,
                              hipStream_t stream) {
    const float* hist    = (const float*)d_in[0];
    const float* emb_W   = (const float*)d_in[1];
    const float* emb_b   = (const float*)d_in[2];
    const float* enc_Wih = (const float*)d_in[3];
    const float* enc_Whh = (const float*)d_in[4];
    const float* enc_bih = (const float*)d_in[5];
    const float* enc_bhh = (const float*)d_in[6];
    const float* dec_Wih = (const float*)d_in[7];
    const float* dec_Whh = (const float*)d_in[8];
    const float* dec_bih = (const float*)d_in[9];
    const float* dec_bhh = (const float*)d_in[10];
    const float* out_W   = (const float*)d_in[11];
    const float* out_b   = (const float*)d_in[12];

    char* ws = (char*)d_ws;
    unsigned short* W0p = (unsigned short*)(ws + 0);
    unsigned short* W1p = (unsigned short*)(ws + 262144);
    float* benc = (float*)(ws + 786432);
    float* bdec = (float*)(ws + 790528);
    float* Me   = (float*)(ws + 794624);
    float* Md   = (float*)(ws + 798720);
    float* ve   = (float*)(ws + 802816);
    float* vd   = (float*)(ws + 804864);

    prep_kernel<<<1024, 256, 0, stream>>>(emb_W, emb_b,
                                          enc_Wih, enc_Whh, dec_Wih, dec_Whh,
                                          enc_bih, enc_bhh, dec_bih, dec_bhh,
                                          W0p, W1p, benc, bdec, Me, Md, ve, vd);
    lstm_kernel<<<256, NT, 0, stream>>>(hist, W0p, W1p,
                                        benc, bdec, Me, Md, ve, vd,
                                        out_W, out_b, (float*)d_out);
}

// Round 9
// 996.323 us; speedup vs baseline: 1.0675x; 1.0675x over previous
//
#include <hip/hip_runtime.h>
#include <stdint.h>

#define NT 512
#define K1 -1.44269504f
#define K2 -2.88539008f

typedef __attribute__((ext_vector_type(8))) __bf16 bf16x8;
typedef __attribute__((ext_vector_type(8))) unsigned short ushort8;
typedef __attribute__((ext_vector_type(4))) float f32x4;

static __device__ __forceinline__ unsigned short f2bf(float f) {
    union { float f; uint32_t u; } v; v.f = f;
    uint32_t r = v.u + 0x7fffu + ((v.u >> 16) & 1u);   // RNE
    return (unsigned short)(r >> 16);
}

#if __has_builtin(__builtin_amdgcn_exp2f)
#define EXP2F(x) __builtin_amdgcn_exp2f(x)
#else
#define EXP2F(x) __expf((x) * 0.69314718f)
#endif

static __device__ __forceinline__ uint32_t pk_bf16(float lo, float hi) {
#if __has_builtin(__builtin_amdgcn_cvt_pk_bf16_f32)
    return __builtin_bit_cast(uint32_t, __builtin_amdgcn_cvt_pk_bf16_f32(lo, hi));
#else
    return ((uint32_t)f2bf(hi) << 16) | (uint32_t)f2bf(lo);
#endif
}

// LSTM cell for 4 rows, plain per-activation rcp (r7 math, r8 bias folding).
// arg -> +inf saturates exactly: rcp(1+inf)=0. No clamps needed.
static __device__ __forceinline__ void cell4(const f32x4* z, const float* cs,
                                             float* c, float* h) {
#pragma unroll
    for (int i = 0; i < 4; ++i) {
        float si = __builtin_amdgcn_rcpf(1.0f + EXP2F(fmaf(z[0][i], K1, cs[0])));
        float sf = __builtin_amdgcn_rcpf(1.0f + EXP2F(fmaf(z[1][i], K1, cs[1])));
        float tg = fmaf(2.0f, __builtin_amdgcn_rcpf(1.0f + EXP2F(fmaf(z[2][i], K2, cs[2]))), -1.0f);
        float so = __builtin_amdgcn_rcpf(1.0f + EXP2F(fmaf(z[3][i], K1, cs[3])));
        c[i] = fmaf(sf, c[i], si * tg);
        float tc = fmaf(2.0f, __builtin_amdgcn_rcpf(1.0f + EXP2F(c[i] * K2)), -1.0f);
        h[i] = so * tc;
    }
}
static __device__ __forceinline__ bf16x8 ld8(const unsigned short* p) {
    return __builtin_bit_cast(bf16x8, *(const ushort8*)p);
}
static __device__ __forceinline__ float swz(float v, int imm) {
    int r;
    if (imm == 0x0010) r = __builtin_amdgcn_ds_swizzle(__builtin_bit_cast(int, v), 0x0010);
    else               r = __builtin_amdgcn_ds_swizzle(__builtin_bit_cast(int, v), 0x0410);
    return __builtin_bit_cast(float, r);
}

// ---- prep: identical packing to round 7/8 ----
__global__ void prep_kernel(
    const float* __restrict__ emb_W, const float* __restrict__ emb_b,
    const float* __restrict__ enc_Wih, const float* __restrict__ enc_Whh,
    const float* __restrict__ dec_Wih, const float* __restrict__ dec_Whh,
    const float* __restrict__ enc_bih, const float* __restrict__ enc_bhh,
    const float* __restrict__ dec_bih, const float* __restrict__ dec_bhh,
    unsigned short* __restrict__ W0p, unsigned short* __restrict__ W1p,
    float* __restrict__ benc, float* __restrict__ bdec,
    float* __restrict__ Me, float* __restrict__ Md,
    float* __restrict__ ve, float* __restrict__ vd)
{
    int idx = blockIdx.x * blockDim.x + threadIdx.x;
    if (idx < 2 * 512 * 256) {
        int net = idx >> 17;
        int rem = idx & 131071;
        int n = rem >> 8, k = rem & 255;
        const float* Wih = net ? dec_Wih : enc_Wih;
        const float* Whh = net ? dec_Whh : enc_Whh;
        float v = (k < 128) ? Wih[(size_t)(512 + n) * 128 + k]
                            : Whh[(size_t)(512 + n) * 128 + k - 128];
        W1p[(size_t)net * 131072 + rem] = f2bf(v);
    }
    if (idx < 2 * 512 * 128) {
        int net = idx >> 16;
        int rem = idx & 65535;
        int j = rem & 7, quad = (rem >> 3) & 3, ln = (rem >> 5) & 15;
        int w = (rem >> 9) & 7, g = (rem >> 12) & 3, c = (rem >> 14) & 3;
        int n = g * 128 + w * 16 + ln;
        int k = c * 32 + quad * 8 + j;
        const float* Whh = net ? dec_Whh : enc_Whh;
        W0p[(size_t)net * 65536 + rem] = f2bf(Whh[(size_t)n * 128 + k]);
    }
    if (idx < 2048) {
        int net = idx >> 10;
        int rem = idx & 1023;
        float v = net ? (dec_bih[rem] + dec_bhh[rem]) : (enc_bih[rem] + enc_bhh[rem]);
        (net ? bdec : benc)[rem] = v;
    }
    if (idx < 1024) {
        int net = idx >> 9, n = idx & 511;
        const float* Wih = net ? dec_Wih : enc_Wih;
        float m0 = 0.f, m1 = 0.f, vv = 0.f;
        for (int k = 0; k < 128; ++k) {
            float wv = Wih[(size_t)n * 128 + k];
            m0 += wv * emb_W[k * 2 + 0];
            m1 += wv * emb_W[k * 2 + 1];
            vv += wv * emb_b[k];
        }
        float* M = net ? Md : Me;
        float* V = net ? vd : ve;
        M[n * 2 + 0] = m0; M[n * 2 + 1] = m1; V[n] = vv;
    }
}

__global__ __launch_bounds__(NT, 2) void lstm_kernel(
    const float* __restrict__ hist,
    const unsigned short* __restrict__ W0p, const unsigned short* __restrict__ W1p,
    const float* __restrict__ benc, const float* __restrict__ bdec,
    const float* __restrict__ Me, const float* __restrict__ Md,
    const float* __restrict__ ve, const float* __restrict__ vd,
    const float* __restrict__ out_W, const float* __restrict__ out_b,
    float* __restrict__ out)
{
    __shared__ __align__(16) unsigned short A1s[2 * 4096];
    __shared__ __align__(16) unsigned short W0Ls[65536];
    __shared__ __align__(16) float histL[16 * 120];

    const int tid = threadIdx.x;
    const int lane = tid & 63;
    const int w = tid >> 6;
    const int ln = lane & 15;
    const int quad = lane >> 4;
    const int row0 = blockIdx.x * 16;
    const int cc0 = w * 16 + ln;
    const int cg = (cc0 >> 3) & 3;

    const unsigned short* a1r = A1s + ln * 32 + ((quad ^ ((ln >> 2) & 3)) * 8);
    unsigned short* a1w = A1s + (cc0 >> 5) * 512 + quad * 128 + ((cg ^ quad) * 8) + (ln & 7);
    // two W0 bases so every read uses a 16-bit immediate offset
    const unsigned short* w0bA = W0Ls + w * 512 + ln * 32 + ((quad ^ ((ln >> 1) & 3)) * 8);
    const unsigned short* w0bB = w0bA + 32768;

    for (int e = tid; e < 256; e += NT) ((uint4*)A1s)[256 + e] = make_uint4(0u, 0u, 0u, 0u);
    for (int e = tid; e < 480; e += NT)
        ((float4*)histL)[e] = ((const float4*)(hist + (size_t)row0 * 120))[e];

    const int nidx = (ln < 2) ? ln : 0;
    const float outbL = out_b[nidx];
    bf16x8 ow[4];
#pragma unroll
    for (int c = 0; c < 4; ++c) {
        unsigned short tmp[8];
#pragma unroll
        for (int j = 0; j < 8; ++j)
            tmp[j] = f2bf(out_W[nidx * 128 + c * 32 + quad * 8 + j]);
        ow[c] = __builtin_bit_cast(bf16x8, *(ushort8*)tmp);
    }

    bf16x8 wl[4][8];                      // persistent layer1 weights
    float M0c[4], M1c[4];
    float cb0v[4], cb0_[4], cb1[4];       // folded bias*k constants
    float c0r[4] = {0.f, 0.f, 0.f, 0.f};
    float c1r[4] = {0.f, 0.f, 0.f, 0.f};
    const f32x4 fz = {0.f, 0.f, 0.f, 0.f};

    auto load_consts = [&](const float* bb, const float* M, const float* V,
                           const unsigned short* W1) {
#pragma unroll
        for (int g = 0; g < 4; ++g) {
            const int n = g * 128 + cc0;
#pragma unroll
            for (int q = 0; q < 8; ++q)
                wl[g][q] = ld8(W1 + (size_t)n * 256 + quad * 8 + q * 32);
            const float kk = (g == 2) ? K2 : K1;
            M0c[g] = M[n * 2 + 0];
            M1c[g] = M[n * 2 + 1];
            cb0v[g] = (bb[n] + V[n]) * kk;
            cb0_[g] = bb[n] * kk;
            cb1[g]  = bb[512 + n] * kk;
        }
    };
    auto copy_w0 = [&](const unsigned short* src) {
        for (int e = tid; e < 8192; e += NT) {
            int d = (e & ~3) | ((e & 3) ^ ((e >> 3) & 3));
            ((uint4*)W0Ls)[d] = ((const uint4*)src)[e];
        }
    };
    auto w0frag = [&](int c, int g) {   // c,g compile-time under unroll
        return ld8(((c < 2) ? w0bA : w0bB) + (c & 1) * 16384 + g * 4096);
    };
    auto store_h = [&](unsigned short* base, const float* h) {
        uint32_t p01 = pk_bf16(h[0], h[1]);
        uint32_t p23 = pk_bf16(h[2], h[3]);
        base[0]  = (unsigned short)p01;
        base[32] = (unsigned short)(p01 >> 16);
        base[64] = (unsigned short)p23;
        base[96] = (unsigned short)(p23 >> 16);
    };

    copy_w0(W0p);
    load_consts(benc, Me, ve, W1p);
    __syncthreads();

    // prologue: h0(0) = f(x(0), h=0, c=0) -> buf0 chunks 0..3
    {
        f32x4 z[4];
#pragma unroll
        for (int i = 0; i < 4; ++i) {
            float x0 = hist[(size_t)(row0 + quad * 4 + i) * 120 + 0];
            float x1 = hist[(size_t)(row0 + quad * 4 + i) * 120 + 1];
#pragma unroll
            for (int g = 0; g < 4; ++g) z[g][i] = fmaf(M0c[g], x0, M1c[g] * x1);
        }
        float hv[4];
        cell4(z, cb0v, c0r, hv);
        store_h(a1w, hv);
    }
    __syncthreads();

    // ======= encoder superphase S_t: layer1(t) + layer0(t+1), 1 barrier =======
    auto enc_step = [&](int t, int buf) {
        bf16x8 af[8];
#pragma unroll
        for (int q = 0; q < 8; ++q)
            af[q] = ld8(a1r + buf * 4096 + q * 512);
        f32x4 acc1[4];
#pragma unroll
        for (int g = 0; g < 4; ++g)
            acc1[g] = __builtin_amdgcn_mfma_f32_16x16x32_bf16(af[0], wl[g][0], fz, 0, 0, 0);
#pragma unroll
        for (int q = 1; q < 8; ++q)
#pragma unroll
            for (int g = 0; g < 4; ++g)
                acc1[g] = __builtin_amdgcn_mfma_f32_16x16x32_bf16(af[q], wl[g][q], acc1[g], 0, 0, 0);
        f32x4 acc0[4];
#pragma unroll
        for (int g = 0; g < 4; ++g)
            acc0[g] = __builtin_amdgcn_mfma_f32_16x16x32_bf16(af[0], w0frag(0, g), fz, 0, 0, 0);
#pragma unroll
        for (int c = 1; c < 4; ++c)
#pragma unroll
            for (int g = 0; g < 4; ++g)
                acc0[g] = __builtin_amdgcn_mfma_f32_16x16x32_bf16(af[c], w0frag(c, g), acc0[g], 0, 0, 0);
        float hv[4];
        cell4(acc1, cb1, c1r, hv);                       // layer1(t)
        store_h(a1w + (buf ^ 1) * 4096 + 2048, hv);
        f32x4 z0[4];
#pragma unroll
        for (int i = 0; i < 4; ++i) {
            float2 pv = *(const float2*)&histL[(quad * 4 + i) * 120 + 2 * (t + 1)];
#pragma unroll
            for (int g = 0; g < 4; ++g)
                z0[g][i] = fmaf(M0c[g], pv.x, fmaf(M1c[g], pv.y, acc0[g][i]));
        }
        cell4(z0, cb0v, c0r, hv);                        // layer0(t+1)
        store_h(a1w + (buf ^ 1) * 4096, hv);
        __syncthreads();
    };

    for (int t = 0; t < 58; t += 2) { enc_step(t, 0); enc_step(t + 1, 1); }
    enc_step(58, 0);

    // ======= S_59: layer1_enc(59); swap to decoder; layer0_dec(0) =======
    {
        bf16x8 af[8];
#pragma unroll
        for (int q = 0; q < 8; ++q)
            af[q] = ld8(a1r + 4096 + q * 512);
        f32x4 acc1[4];
#pragma unroll
        for (int g = 0; g < 4; ++g)
            acc1[g] = __builtin_amdgcn_mfma_f32_16x16x32_bf16(af[0], wl[g][0], fz, 0, 0, 0);
#pragma unroll
        for (int q = 1; q < 8; ++q)
#pragma unroll
            for (int g = 0; g < 4; ++g)
                acc1[g] = __builtin_amdgcn_mfma_f32_16x16x32_bf16(af[q], wl[g][q], acc1[g], 0, 0, 0);
        float hv[4];
        cell4(acc1, cb1, c1r, hv);
        store_h(a1w + 2048, hv);                         // h1(59) -> buf0[4..7]
        copy_w0(W0p + 65536);
        load_consts(bdec, Md, vd, W1p + 131072);
        __syncthreads();
        f32x4 acc0[4];
#pragma unroll
        for (int g = 0; g < 4; ++g)
            acc0[g] = __builtin_amdgcn_mfma_f32_16x16x32_bf16(af[0], w0frag(0, g), fz, 0, 0, 0);
#pragma unroll
        for (int c = 1; c < 4; ++c)
#pragma unroll
            for (int g = 0; g < 4; ++g)
                acc0[g] = __builtin_amdgcn_mfma_f32_16x16x32_bf16(af[c], w0frag(c, g), acc0[g], 0, 0, 0);
        cell4(acc0, cb0_, c0r, hv);                      // x = 0 at d=0
        store_h(a1w, hv);                                // h0_d(0) -> buf0[0..3]
        __syncthreads();
    }

    // ======= decoder D_d: ph1 layer1(d)+W0·h0(d); ph2 proj(d)+layer0(d+1) =======
    auto dec_step = [&](int d, int buf) {
        bf16x8 af[8];
#pragma unroll
        for (int q = 0; q < 8; ++q)
            af[q] = ld8(a1r + buf * 4096 + q * 512);
        f32x4 acc1[4];
#pragma unroll
        for (int g = 0; g < 4; ++g)
            acc1[g] = __builtin_amdgcn_mfma_f32_16x16x32_bf16(af[0], wl[g][0], fz, 0, 0, 0);
#pragma unroll
        for (int q = 1; q < 8; ++q)
#pragma unroll
            for (int g = 0; g < 4; ++g)
                acc1[g] = __builtin_amdgcn_mfma_f32_16x16x32_bf16(af[q], wl[g][q], acc1[g], 0, 0, 0);
        f32x4 acc0[4];
#pragma unroll
        for (int g = 0; g < 4; ++g)
            acc0[g] = __builtin_amdgcn_mfma_f32_16x16x32_bf16(af[0], w0frag(0, g), fz, 0, 0, 0);
#pragma unroll
        for (int c = 1; c < 4; ++c)
#pragma unroll
            for (int g = 0; g < 4; ++g)
                acc0[g] = __builtin_amdgcn_mfma_f32_16x16x32_bf16(af[c], w0frag(c, g), acc0[g], 0, 0, 0);
        float hv[4];
        cell4(acc1, cb1, c1r, hv);                       // layer1(d)
        store_h(a1w + (buf ^ 1) * 4096 + 2048, hv);
        __syncthreads();
        // phase 2: projection of h1(d)
        f32x4 pa = fz, pb = fz;
        pa = __builtin_amdgcn_mfma_f32_16x16x32_bf16(ld8(a1r + (buf ^ 1) * 4096 + 4 * 512), ow[0], pa, 0, 0, 0);
        pb = __builtin_amdgcn_mfma_f32_16x16x32_bf16(ld8(a1r + (buf ^ 1) * 4096 + 5 * 512), ow[1], pb, 0, 0, 0);
        pa = __builtin_amdgcn_mfma_f32_16x16x32_bf16(ld8(a1r + (buf ^ 1) * 4096 + 6 * 512), ow[2], pa, 0, 0, 0);
        pb = __builtin_amdgcn_mfma_f32_16x16x32_bf16(ld8(a1r + (buf ^ 1) * 4096 + 7 * 512), ow[3], pb, 0, 0, 0);
        float pd[4];
#pragma unroll
        for (int i = 0; i < 4; ++i) pd[i] = pa[i] + pb[i] + outbL;
        if (w == 0 && ln < 2) {
#pragma unroll
            for (int i = 0; i < 4; ++i)
                out[(size_t)(row0 + quad * 4 + i) * 720 + (size_t)d * 2 + ln] = pd[i];
        }
        f32x4 z0[4];
#pragma unroll
        for (int i = 0; i < 4; ++i) {
            float p0 = swz(pd[i], 0x0010);
            float p1 = swz(pd[i], 0x0410);
#pragma unroll
            for (int g = 0; g < 4; ++g)
                z0[g][i] = fmaf(M0c[g], p0, fmaf(M1c[g], p1, acc0[g][i]));
        }
        cell4(z0, cb0v, c0r, hv);                        // layer0(d+1)
        store_h(a1w + (buf ^ 1) * 4096, hv);
        __syncthreads();
    };

    for (int d = 0; d < 360; d += 2) { dec_step(d, 0); dec_step(d + 1, 1); }

    // final projection (h1(359) lives in buffer 0)
    {
        f32x4 pacc = fz;
#pragma unroll
        for (int c = 0; c < 4; ++c) {
            bf16x8 ah = ld8(a1r + 0 * 4096 + (4 + c) * 512);
            pacc = __builtin_amdgcn_mfma_f32_16x16x32_bf16(ah, ow[c], pacc, 0, 0, 0);
        }
        if (w == 0 && ln < 2) {
#pragma unroll
            for (int i = 0; i < 4; ++i)
                out[(size_t)(row0 + quad * 4 + i) * 720 + 359 * 2 + ln] = pacc[i] + outbL;
        }
    }
}

extern "C" void kernel_launch(void* const* d_in, const int* in_sizes, int n_in,
                              void* d_out, int out_size, void* d_ws, size_t ws_size,
                              hipStream_t stream) {
    const float* hist    = (const float*)d_in[0];
    const float* emb_W   = (const float*)d_in[1];
    const float* emb_b   = (const float*)d_in[2];
    const float* enc_Wih = (const float*)d_in[3];
    const float* enc_Whh = (const float*)d_in[4];
    const float* enc_bih = (const float*)d_in[5];
    const float* enc_bhh = (const float*)d_in[6];
    const float* dec_Wih = (const float*)d_in[7];
    const float* dec_Whh = (const float*)d_in[8];
    const float* dec_bih = (const float*)d_in[9];
    const float* dec_bhh = (const float*)d_in[10];
    const float* out_W   = (const float*)d_in[11];
    const float* out_b   = (const float*)d_in[12];

    char* ws = (char*)d_ws;
    unsigned short* W0p = (unsigned short*)(ws + 0);
    unsigned short* W1p = (unsigned short*)(ws + 262144);
    float* benc = (float*)(ws + 786432);
    float* bdec = (float*)(ws + 790528);
    float* Me   = (float*)(ws + 794624);
    float* Md   = (float*)(ws + 798720);
    float* ve   = (float*)(ws + 802816);
    float* vd   = (float*)(ws + 804864);

    prep_kernel<<<1024, 256, 0, stream>>>(emb_W, emb_b,
                                          enc_Wih, enc_Whh, dec_Wih, dec_Whh,
                                          enc_bih, enc_bhh, dec_bih, dec_bhh,
                                          W0p, W1p, benc, bdec, Me, Md, ve, vd);
    lstm_kernel<<<256, NT, 0, stream>>>(hist, W0p, W1p,
                                        benc, bdec, Me, Md, ve, vd,
                                        out_W, out_b, (float*)d_out);
}